// Round 20
// baseline (41.971 us; speedup 1.0000x reference)
//
#include <hip/hip_runtime.h>

// Chamfer via MFMA, single-pass over the distance matrix.
// D[i][j] = ||p_i - r_j||^2 built inside mfma_f32_16x16x32_f16 via K-slots
// (pack format HW-proven in round 19, absmax 0.0):
//  A(pt):  g0=[-2xh,-2xh,-2xl,-2yh,-2yh,-2yl, nh, nl] g1=[8,8,0...] g2=g3=0
//  B(ref): g0=[xh,  xl,  xh,  yh,  yl,  yh,  8,  8 ] g1=[nh,nl,0..] g2=g3=0
//  (h/l = f16 hi/lo split; n = ||q||^2/8 hi/lo; C/D: col=lane&15,
//   row=(lane>>4)*4+reg — HW-verified.)
// Each 16x16 tile feeds BOTH row-mins (pts) and col-mins (refs): matrix
// computed once. Grid 8x32 blocks: block = 512 pts x 1024 refs; B staged in
// LDS (2 chunks x 32KB); col-mins via LDS atomicMin (uint, deterministic).
// Partials: rowpart[32][4096], colpart[8][32768] (1.5MB) -> 72-block fold.

typedef _Float16 half8 __attribute__((ext_vector_type(8)));
typedef float f32x4 __attribute__((ext_vector_type(4)));

constexpr int N_PTS = 4096;
constexpr int M_REF = 32768;
constexpr int APo = 0;                  // pts A-format:  256 tiles * 64 u4
constexpr int BPo = 16384;              // refs B-format: 2048 tiles * 64 u4
constexpr int PART_U4 = BPo + 131072;   // partial arrays start (u4 units)

__device__ __forceinline__ unsigned int pk2(float a, float b) {
    _Float16 ha = (_Float16)a, hb = (_Float16)b;
    unsigned short ua = *(unsigned short*)&ha, ub = *(unsigned short*)&hb;
    return (unsigned int)ua | ((unsigned int)ub << 16);
}

// ---------------- Kernel 0: pack fragments (proven format) -----------------
__global__ __launch_bounds__(256) void pack_kernel(
    const float2* __restrict__ pts, const float2* __restrict__ refs,
    uint4* __restrict__ ws4, float* __restrict__ out)
{
    const int gid = blockIdx.x * 256 + threadIdx.x;   // 144*256 = 36864
    if (gid == 0) out[0] = 0.f;
    float2 p; uint4* Dd; bool isA;
    if (gid < N_PTS) { p = pts[gid];  Dd = ws4 + APo + (gid >> 4) * 64 + (gid & 15); isA = true; }
    else { const int q = gid - N_PTS; p = refs[q]; Dd = ws4 + BPo + (q >> 4) * 64 + (q & 15); isA = false; }
    const float x = p.x, y = p.y;
    const _Float16 xh = (_Float16)x; const float fxh = (float)xh, xl = x - fxh;
    const _Float16 yh = (_Float16)y; const float fyh = (float)yh, yl = y - fyh;
    const float n8 = fmaf(x, x, y * y) * 0.125f;
    const _Float16 nh = (_Float16)n8; const float fnh = (float)nh, nl = n8 - fnh;
    const uint4 z4 = make_uint4(0, 0, 0, 0);
    if (isA) {
        Dd[0]  = make_uint4(pk2(-2.f*fxh, -2.f*fxh), pk2(-2.f*xl, -2.f*fyh),
                            pk2(-2.f*fyh, -2.f*yl),  pk2(fnh, nl));
        Dd[16] = make_uint4(pk2(8.f, 8.f), 0, 0, 0);
    } else {
        Dd[0]  = make_uint4(pk2(fxh, xl), pk2(fxh, fyh), pk2(yl, fyh), pk2(8.f, 8.f));
        Dd[16] = make_uint4(pk2(fnh, nl), 0, 0, 0);
    }
    Dd[32] = z4; Dd[48] = z4;
}

// ---------------- Kernel 1: MFMA main, 256 blocks x 512 threads ------------
__global__ __launch_bounds__(512) void mfma_main(
    const uint4* __restrict__ ws4,
    float* __restrict__ rowpart,   // [32][4096]
    float* __restrict__ colpart)   // [8][32768]
{
    __shared__ uint4 Bs[2048];               // 32 B-tiles = 32 KB
    __shared__ unsigned int colredU[1024];   // per-block col mins (uint bits)
    const int tid = threadIdx.x, b = blockIdx.x;
    const int bi = b >> 5, bj = b & 31;      // 8 x 32 grid
    const int l = tid & 63, w = tid >> 6;
    const f32x4 zc = {0.f, 0.f, 0.f, 0.f};

    colredU[tid] = 0x7F7F7F7Fu; colredU[tid + 512] = 0x7F7F7F7Fu;

    half8 Am[4];
    #pragma unroll
    for (int m = 0; m < 4; ++m) {
        uint4 a = ws4[APo + (bi * 32 + w * 4 + m) * 64 + l];
        Am[m] = *reinterpret_cast<half8*>(&a);
    }
    float rowmin[4][4];
    #pragma unroll
    for (int m = 0; m < 4; ++m)
        #pragma unroll
        for (int r = 0; r < 4; ++r) rowmin[m][r] = 3.0e38f;

    for (int chunk = 0; chunk < 2; ++chunk) {
        __syncthreads();
        #pragma unroll
        for (int u = 0; u < 4; ++u)
            Bs[tid + 512 * u] = ws4[BPo + bj * 4096 + chunk * 2048 + tid + 512 * u];
        __syncthreads();
        for (int j = 0; j < 32; ++j) {
            uint4 bq = Bs[j * 64 + l];
            const half8 B = *reinterpret_cast<half8*>(&bq);
            float colv = 3.0e38f;
            #pragma unroll
            for (int m = 0; m < 4; ++m) {
                const f32x4 D = __builtin_amdgcn_mfma_f32_16x16x32_f16(Am[m], B, zc, 0, 0, 0);
                rowmin[m][0] = fminf(rowmin[m][0], D[0]);
                rowmin[m][1] = fminf(rowmin[m][1], D[1]);
                rowmin[m][2] = fminf(rowmin[m][2], D[2]);
                rowmin[m][3] = fminf(rowmin[m][3], D[3]);
                colv = fminf(fminf(fminf(fminf(colv, D[0]), D[1]), D[2]), D[3]);
            }
            colv = fminf(colv, __shfl_xor(colv, 16, 64));
            colv = fminf(colv, __shfl_xor(colv, 32, 64));
            colv = fmaxf(colv, 0.f);             // nonneg -> uint order-preserving
            if (l < 16)
                atomicMin(&colredU[(chunk * 32 + j) * 16 + l], __float_as_uint(colv));
        }
    }

    // Row-mins: fold over the 16 cols (lanes within group), then store.
    #pragma unroll
    for (int m = 0; m < 4; ++m)
        #pragma unroll
        for (int r = 0; r < 4; ++r)
            #pragma unroll
            for (int mk = 1; mk < 16; mk <<= 1)
                rowmin[m][r] = fminf(rowmin[m][r], __shfl_xor(rowmin[m][r], mk, 64));
    if ((l & 15) == 0) {
        const int r0 = (l >> 4) * 4;
        #pragma unroll
        for (int m = 0; m < 4; ++m)
            #pragma unroll
            for (int r = 0; r < 4; ++r)
                rowpart[bj * 4096 + bi * 512 + (w * 4 + m) * 16 + r0 + r] = rowmin[m][r];
    }
    __syncthreads();
    // Col-mins -> colpart (written exactly once).
    colpart[bi * 32768 + bj * 1024 + tid]       = __uint_as_float(colredU[tid]);
    colpart[bi * 32768 + bj * 1024 + tid + 512] = __uint_as_float(colredU[tid + 512]);
}

// ---------------- Kernel 2: fold + sqrt + accumulate (72 blocks) -----------
__global__ __launch_bounds__(256) void fold_kernel(
    const float4* __restrict__ rowpart4,   // [32][1024]
    const float4* __restrict__ colpart4,   // [8][8192]
    float* __restrict__ out)
{
    __shared__ float4 shm[128];
    __shared__ float ss[4];
    const int tid = threadIdx.x, b = blockIdx.x;
    const int lane = tid & 127, sc = tid >> 7;
    const float4* src; int idx, stride, hs;
    if (b < 8) { src = rowpart4; idx = b * 128 + lane;        stride = 1024; hs = 16; }
    else       { src = colpart4; idx = (b - 8) * 128 + lane;  stride = 8192; hs = 4;  }

    float4 m = src[(sc * hs) * stride + idx];
    for (int s = 1; s < hs; ++s) {
        const float4 v = src[(sc * hs + s) * stride + idx];
        m.x = fminf(m.x, v.x); m.y = fminf(m.y, v.y);
        m.z = fminf(m.z, v.z); m.w = fminf(m.w, v.w);
    }
    if (sc) shm[lane] = m;
    __syncthreads();
    float sum = 0.f;
    if (!sc) {
        const float4 o = shm[lane];
        m.x = fminf(m.x, o.x); m.y = fminf(m.y, o.y);
        m.z = fminf(m.z, o.z); m.w = fminf(m.w, o.w);
        sum = sqrtf(fmaxf(m.x, 1e-12f)) + sqrtf(fmaxf(m.y, 1e-12f))
            + sqrtf(fmaxf(m.z, 1e-12f)) + sqrtf(fmaxf(m.w, 1e-12f));
    }
    #pragma unroll
    for (int off = 32; off > 0; off >>= 1) sum += __shfl_down(sum, off, 64);
    if ((tid & 63) == 0) ss[tid >> 6] = sum;
    __syncthreads();
    if (tid == 0) atomicAdd(out, ss[0] + ss[1] + ss[2] + ss[3]);
}

extern "C" void kernel_launch(void* const* d_in, const int* in_sizes, int n_in,
                              void* d_out, int out_size, void* d_ws, size_t ws_size,
                              hipStream_t stream) {
    const float2* pts  = (const float2*)d_in[0];            // circle 0 (offset 0)
    const float2* refs = ((const float2*)d_in[1]) + M_REF;  // last (=2nd) skeleton slice

    uint4* ws4 = (uint4*)d_ws;
    float* rowpart = (float*)(ws4 + PART_U4);               // 32*4096 floats
    float* colpart = rowpart + 32 * 4096;                   //  8*32768 floats
    float* out = (float*)d_out;

    pack_kernel<<<144, 256, 0, stream>>>(pts, refs, ws4, out);
    mfma_main  <<<256, 512, 0, stream>>>(ws4, rowpart, colpart);
    fold_kernel<<<72, 256, 0, stream>>>((const float4*)rowpart,
                                        (const float4*)colpart, out);
}